// Round 3
// baseline (240.992 us; speedup 1.0000x reference)
//
#include <hip/hip_runtime.h>

typedef float floatx4 __attribute__((ext_vector_type(4)));
typedef __bf16 bfx8 __attribute__((ext_vector_type(8)));
typedef __bf16 bfx4 __attribute__((ext_vector_type(4)));

// Problem constants
constexpr int B_ = 2, S_ = 2048, H_ = 2048, NH_ = 16, NKV_ = 4, HD_ = 64;
constexpr int M_ = B_ * S_;               // 4096 rows
constexpr int NQKV_ = NH_ * HD_ + 2 * NKV_ * HD_; // 1536
constexpr int HQ_ = NH_ * HD_;            // 1024
// Padded pitches (break 4KB/2KB row strides -> channel aliasing)
constexpr int XP_ = 2056;  // xbf / wqkvT pitch
constexpr int AP_ = 1032;  // attn-out / woT pitch
constexpr int VP_ = 2056;  // V-transposed pitch
// split-K partial stride (elements) for the QKV GEMM
constexpr int QKV_ELEMS_ = M_ * NQKV_;    // 6,291,456

#define GLB(p) ((const __attribute__((address_space(1))) void*)(p))
#define LDS(p) ((__attribute__((address_space(3))) void*)(p))

// ---------------- fused prep: fp32->bf16 cast of x  +  all 4 weight transposes ----------
__global__ __launch_bounds__(256) void prep_kernel(const float* __restrict__ x,
                                                   const float* __restrict__ wq,
                                                   const float* __restrict__ wk,
                                                   const float* __restrict__ wv,
                                                   const float* __restrict__ wo,
                                                   __bf16* __restrict__ xbf,
                                                   __bf16* __restrict__ wqkvT,
                                                   __bf16* __restrict__ woT) {
  __shared__ float tile[32][33];
  int bid = blockIdx.x;
  if (bid < M_) {
    // ---- cast branch ----
    const float4* s = (const float4*)(x + (size_t)bid * H_);
    __bf16* d = xbf + (size_t)bid * XP_;
#pragma unroll
    for (int i = 0; i < 2; i++) {
      int c = i * 256 + threadIdx.x;
      float4 v = s[c];
      bfx4 o;
      o[0] = (__bf16)v.x; o[1] = (__bf16)v.y; o[2] = (__bf16)v.z; o[3] = (__bf16)v.w;
      *(bfx4*)(d + c * 4) = o;
    }
    return;
  }
  bid -= M_;
  const float* src; __bf16* dst; int N, dstOff, pitch, nbx;
  if (bid < 2048)      { src = wq; dst = wqkvT; N = 1024; dstOff = 0;    pitch = XP_; nbx = 32; }
  else if (bid < 2560) { bid -= 2048; src = wk; dst = wqkvT; N = 256; dstOff = 1024; pitch = XP_; nbx = 8; }
  else if (bid < 3072) { bid -= 2560; src = wv; dst = wqkvT; N = 256; dstOff = 1280; pitch = XP_; nbx = 8; }
  else                 { bid -= 3072; src = wo; dst = woT;   N = 2048; dstOff = 0;   pitch = AP_; nbx = 64; }
  int n0 = (bid % nbx) * 32, k0 = (bid / nbx) * 32;
  int tx = threadIdx.x & 31, ty = threadIdx.x >> 5; // (32,8) layout
#pragma unroll
  for (int r = 0; r < 32; r += 8)
    tile[ty + r][tx] = src[(size_t)(k0 + ty + r) * N + n0 + tx];
  __syncthreads();
#pragma unroll
  for (int r = 0; r < 32; r += 8)
    dst[(size_t)(n0 + ty + r + dstOff) * pitch + k0 + tx] = (__bf16)tile[tx][ty + r];
}

// ---------------- bf16 MFMA GEMM: 256x128 tile, BK=64, 8 waves (4m x 2n) ------------
__global__ __launch_bounds__(512) void gemm_bf16_f32(const __bf16* __restrict__ A,
                                                     const __bf16* __restrict__ Bt,
                                                     float* __restrict__ C,
                                                     int M, int N, int K,
                                                     int lda, int ldb, int ldc,
                                                     unsigned long long cstride) {
  __shared__ __align__(16) __bf16 As[256 * 64];
  __shared__ __align__(16) __bf16 Bs[128 * 64];
  int wid = threadIdx.x >> 6, lane = threadIdx.x & 63;
  int l15 = lane & 15, quad = lane >> 4;
  int wm = (wid >> 1) * 64, wn = (wid & 1) * 64; // 4m x 2n wave grid
  int m0 = blockIdx.y * 256, n0 = blockIdx.x * 128;
  int kb0 = blockIdx.z * K;
  C += (size_t)blockIdx.z * cstride;
  int srow_off = lane >> 3;  // 8 lanes per 64-col row (16B each)
  int gphys = lane & 7;
  floatx4 acc[4][4] = {};
  for (int kb = kb0; kb < kb0 + K; kb += 64) {
#pragma unroll
    for (int j = 0; j < 4; j++) {
      int rbase = j * 64 + wid * 8;
      int row = rbase + srow_off;
      int glog = gphys ^ (row & 7);
      const __bf16* ga = &A[(size_t)(m0 + row) * lda + kb + glog * 8];
      __builtin_amdgcn_global_load_lds(GLB(ga), LDS(&As[rbase * 64]), 16, 0, 0);
    }
#pragma unroll
    for (int j = 0; j < 2; j++) {
      int rbase = j * 64 + wid * 8;
      int row = rbase + srow_off;
      int glog = gphys ^ (row & 7);
      const __bf16* gb = &Bt[(size_t)(n0 + row) * ldb + kb + glog * 8];
      __builtin_amdgcn_global_load_lds(GLB(gb), LDS(&Bs[rbase * 64]), 16, 0, 0);
    }
    __syncthreads(); // compiler emits vmcnt(0) drain before barrier
#pragma unroll
    for (int kk = 0; kk < 64; kk += 32) {
      int cgq = (kk >> 3) + quad; // logical 16B-group of this quad's fragment
      bfx8 af[4], bfr[4];
#pragma unroll
      for (int mi = 0; mi < 4; mi++) {
        int row = wm + mi * 16 + l15;
        af[mi] = *(const bfx8*)&As[row * 64 + (cgq ^ (row & 7)) * 8];
      }
#pragma unroll
      for (int ni = 0; ni < 4; ni++) {
        int row = wn + ni * 16 + l15;
        bfr[ni] = *(const bfx8*)&Bs[row * 64 + (cgq ^ (row & 7)) * 8];
      }
#pragma unroll
      for (int mi = 0; mi < 4; mi++)
#pragma unroll
        for (int ni = 0; ni < 4; ni++)
          acc[mi][ni] = __builtin_amdgcn_mfma_f32_16x16x32_bf16(af[mi], bfr[ni], acc[mi][ni], 0, 0, 0);
    }
    __syncthreads();
  }
#pragma unroll
  for (int mi = 0; mi < 4; mi++)
#pragma unroll
    for (int ni = 0; ni < 4; ni++) {
      int row = m0 + wm + mi * 16 + quad * 4;
      int coln = n0 + wn + ni * 16 + l15;
#pragma unroll
      for (int r = 0; r < 4; r++)
        C[(size_t)(row + r) * ldc + coln] = acc[mi][ni][r];
    }
}

// ---------------- RMSNorm + RoPE on q/k, cast+layout for attention ----------------
__global__ __launch_bounds__(256) void norm_rope_kernel(const float* __restrict__ qkv,
                                                        const float* __restrict__ cosT,
                                                        const float* __restrict__ sinT,
                                                        const float* __restrict__ qw,
                                                        const float* __restrict__ kw,
                                                        __bf16* __restrict__ Qo,
                                                        __bf16* __restrict__ Ko,
                                                        __bf16* __restrict__ VTo) {
  int s = blockIdx.x, b = blockIdx.y;
  int wid = threadIdx.x >> 6, lane = threadIdx.x & 63;
  const float* rowp = qkv + (size_t)(b * S_ + s) * NQKV_;
  const float* rowp2 = rowp + QKV_ELEMS_;
  float c = cosT[s * HD_ + lane];
  float sn = sinT[s * HD_ + lane];
#pragma unroll
  for (int it = 0; it < 5; it++) {
    int hh = it * 4 + wid; // 0..15 q heads, 16..19 k heads
    int idx = hh * 64 + lane;
    float v = rowp[idx] + rowp2[idx];
    float ss = v * v;
#pragma unroll
    for (int off = 1; off < 64; off <<= 1) ss += __shfl_xor(ss, off);
    float rs = rsqrtf(ss * (1.0f / 64.0f) + 1e-6f);
    const float* w = (hh < 16) ? qw : kw;
    float nv = v * rs * w[lane];
    float other = __shfl_xor(nv, 32);
    float rot = (lane < 32) ? -other : other; // rotate_half
    float outv = nv * c + rot * sn;
    if (hh < 16)
      Qo[(((size_t)b * NH_ + hh) * S_ + s) * HD_ + lane] = (__bf16)outv;
    else
      Ko[(((size_t)b * NKV_ + (hh - 16)) * S_ + s) * HD_ + lane] = (__bf16)outv;
  }
  {
    int idx = (20 + wid) * 64 + lane;
    float v = rowp[idx] + rowp2[idx];
    VTo[(((size_t)b * NKV_ + wid) * HD_ + lane) * VP_ + s] = (__bf16)v;
  }
}

// ---------------- flash attention (causal, GQA) ----------------
// QBLK=128, 8 waves, each wave owns 16 q-rows. K/V staged by double-buffered
// global_load_lds into LINEAR LDS [64][64] with XOR swizzle applied to the SOURCE
// address (GEMM's zero-conflict pattern); fragment reads undo the swizzle.
// One barrier per kv-tile: barrier -> issue DMA for tile t+1 -> compute tile t.
// Mask peeled: per wave exactly one partial tile (kt == q0w/64); earlier tiles
// unmasked; later tiles staging+barrier only (wave-uniform control flow).
__global__ __launch_bounds__(512, 4) void attn_kernel(const __bf16* __restrict__ Q,
                                                      const __bf16* __restrict__ Kc,
                                                      const __bf16* __restrict__ VT,
                                                      __bf16* __restrict__ Ob) {
  int px = blockIdx.x, h = blockIdx.y, b = blockIdx.z;
  int u = (px + 2 * (h & 7)) & 15;
  int qt = (((h >> 3) ^ b) & 1) ? (15 - u) : u;
  int wid = threadIdx.x >> 6, lane = threadIdx.x & 63;
  int l15 = lane & 15, quad = lane >> 4;
  int q0w = qt * 128 + wid * 16;
  int kvh = h >> 2; // N_REP = 4
  const __bf16* Qh = Q + (((size_t)b * NH_ + h) * S_ + q0w) * HD_;
  const __bf16* Kh = Kc + ((size_t)b * NKV_ + kvh) * S_ * HD_;
  const __bf16* Vh = VT + ((size_t)b * NKV_ + kvh) * (size_t)HD_ * VP_;
  __shared__ __align__(16) __bf16 Ks2[2][64 * 64]; // [kv][hd], source-swizzled
  __shared__ __align__(16) __bf16 Vs2[2][64 * 64]; // [hd][kv], source-swizzled
  __shared__ __align__(16) __bf16 Pst[8][16][72];
  __bf16 (*P)[72] = Pst[wid];

  // staging: wave wid covers rows [wid*8, wid*8+8) of each 64x64 tile.
  // lane -> row wid*8 + (lane>>3), physical 16B-group lane&7,
  // source logical group (lane&7) ^ (row&7)  (LDS stays linear; reads undo the XOR)
  int srow = wid * 8 + (lane >> 3);
  int gph = (lane & 7) ^ (srow & 7);
  const __bf16* gK = Kh + (size_t)srow * HD_ + gph * 8;
  const __bf16* gV = Vh + (size_t)srow * VP_ + gph * 8;
  int ldsOff = wid * 8 * 64;

  bfx8 qf0, qf1;
  {
    const __bf16* qp = Qh + l15 * HD_ + quad * 8;
    qf0 = *(const bfx8*)qp;
    qf1 = *(const bfx8*)(qp + 32);
  }
  floatx4 oacc[4] = {};
  float ps = 0.f;
  int ntiles = 2 * qt + 2;      // block-uniform
  int ktmask = q0w >> 6;        // this wave's single partial tile
  constexpr float SCL = 0.125f * 1.44269504088896340736f; // fold 1/sqrt(64) into exp2

  // prologue: stage tile 0 into buffer 0
  __builtin_amdgcn_global_load_lds(GLB(gK), LDS(&Ks2[0][ldsOff]), 16, 0, 0);
  __builtin_amdgcn_global_load_lds(GLB(gV), LDS(&Vs2[0][ldsOff]), 16, 0, 0);

  for (int kt = 0; kt < ntiles; kt++) {
    int buf = kt & 1;
    __syncthreads(); // staging of buf complete (compiler drains vmcnt before barrier)
    if (kt + 1 < ntiles) {
      int kn = (kt + 1) * 64;
      __builtin_amdgcn_global_load_lds(GLB(gK + (size_t)kn * HD_), LDS(&Ks2[buf ^ 1][ldsOff]), 16, 0, 0);
      __builtin_amdgcn_global_load_lds(GLB(gV + kn), LDS(&Vs2[buf ^ 1][ldsOff]), 16, 0, 0);
    }
    if (kt > ktmask) continue; // wave-uniform: stage+barrier only

    const __bf16* Ksb = Ks2[buf];
    const __bf16* Vsb = Vs2[buf];
    floatx4 sf[4];
#pragma unroll
    for (int nt = 0; nt < 4; nt++) {
      int r = nt * 16 + l15;
      int pg = (quad ^ (r & 7)) * 8;
      bfx8 kf0 = *(const bfx8*)&Ksb[r * 64 + pg];
      bfx8 kf1 = *(const bfx8*)&Ksb[r * 64 + (pg ^ 32)];
      floatx4 z = {0.f, 0.f, 0.f, 0.f};
      z = __builtin_amdgcn_mfma_f32_16x16x32_bf16(kf0, qf0, z, 0, 0, 0);
      sf[nt] = __builtin_amdgcn_mfma_f32_16x16x32_bf16(kf1, qf1, z, 0, 0, 0);
    }
    if (kt < ktmask) {
      // fully unmasked tile: no compare/cndmask
#pragma unroll
      for (int nt = 0; nt < 4; nt++) {
        bfx4 pk;
#pragma unroll
        for (int r = 0; r < 4; r++) {
          float p = exp2f(sf[nt][r] * SCL);
          ps += p;
          pk[r] = (__bf16)p;
        }
        *(bfx4*)&P[l15][nt * 16 + quad * 4] = pk;
      }
    } else {
      int dq = q0w - kt * 64;
#pragma unroll
      for (int nt = 0; nt < 4; nt++) {
        bfx4 pk;
#pragma unroll
        for (int r = 0; r < 4; r++) {
          int kvrel = nt * 16 + quad * 4 + r;
          float p = exp2f(sf[nt][r] * SCL);
          p = (kvrel - l15 > dq) ? 0.f : p;
          ps += p;
          pk[r] = (__bf16)p;
        }
        *(bfx4*)&P[l15][nt * 16 + quad * 4] = pk;
      }
    }
    bfx8 pa0 = *(const bfx8*)&P[l15][quad * 8];
    bfx8 pa1 = *(const bfx8*)&P[l15][32 + quad * 8];
#pragma unroll
    for (int ot = 0; ot < 4; ot++) {
      int d = ot * 16 + l15;
      int vg = (quad ^ (d & 7)) * 8;
      bfx8 vf0 = *(const bfx8*)&Vsb[d * 64 + vg];
      bfx8 vf1 = *(const bfx8*)&Vsb[d * 64 + (vg ^ 32)];
      oacc[ot] = __builtin_amdgcn_mfma_f32_16x16x32_bf16(pa0, vf0, oacc[ot], 0, 0, 0);
      oacc[ot] = __builtin_amdgcn_mfma_f32_16x16x32_bf16(pa1, vf1, oacc[ot], 0, 0, 0);
    }
  }
  ps += __shfl_xor(ps, 16);
  ps += __shfl_xor(ps, 32);
  float rl[4];
#pragma unroll
  for (int r = 0; r < 4; r++) rl[r] = 1.0f / __shfl(ps, quad * 4 + r);
#pragma unroll
  for (int ot = 0; ot < 4; ot++)
#pragma unroll
    for (int r = 0; r < 4; r++) {
      float val = oacc[ot][r] * rl[r];
      Ob[((size_t)b * S_ + q0w + quad * 4 + r) * AP_ + h * HD_ + ot * 16 + l15] = (__bf16)val;
    }
}

extern "C" void kernel_launch(void* const* d_in, const int* in_sizes, int n_in,
                              void* d_out, int out_size, void* d_ws, size_t ws_size,
                              hipStream_t stream) {
  const float* x   = (const float*)d_in[0];
  const float* cosT = (const float*)d_in[1];
  const float* sinT = (const float*)d_in[2];
  const float* wq  = (const float*)d_in[3];
  const float* wk  = (const float*)d_in[4];
  const float* wv  = (const float*)d_in[5];
  const float* wo  = (const float*)d_in[6];
  const float* qw  = (const float*)d_in[7];
  const float* kw  = (const float*)d_in[8];
  float* out = (float*)d_out;

  char* w = (char*)d_ws;
  __bf16* xbf   = (__bf16*)(w);                        // 4096*2056*2 = 16,842,752
  __bf16* wqkvT = (__bf16*)(w + 16842752);             // 1536*2056*2 =  6,316,032
  __bf16* woT   = (__bf16*)(w + 23158784);             // 2048*1032*2 =  4,227,072
  float*  qkv   = (float*) (w + 27385856);             // 2 splits * 4096*1536*4 = 50,331,648
  __bf16* attnO = (__bf16*)(w + 27385856);             // aliases qkv (dead after norm_rope)
  __bf16* Qb    = (__bf16*)(w + 77717504);             //  8,388,608
  __bf16* Kb    = (__bf16*)(w + 86106112);             //  2,097,152
  __bf16* VTb   = (__bf16*)(w + 88203264);             //  2,105,344 (end 90,308,608)

  // fused prep: cast (4096 blocks) + wq/wk/wv/wo transposes (2048+512+512+2048)
  prep_kernel<<<M_ + 5120, 256, 0, stream>>>(x, wq, wk, wv, wo, xbf, wqkvT, woT);
  // QKV GEMM, 256x128 tile, split-K=2: grid 12 x 16 x 2 = 384 blocks
  gemm_bf16_f32<<<dim3(NQKV_ / 128, M_ / 256, 2), 512, 0, stream>>>(
      xbf, wqkvT, qkv, M_, NQKV_, H_ / 2, XP_, XP_, NQKV_, (unsigned long long)QKV_ELEMS_);
  norm_rope_kernel<<<dim3(S_, B_), 256, 0, stream>>>(qkv, cosT, sinT, qw, kw, Qb, Kb, VTb);
  // attention: QBLK=128, 8 waves, grid 16 x 16 x 2 = 512 blocks
  attn_kernel<<<dim3(S_ / 128, NH_, B_), 512, 0, stream>>>(Qb, Kb, VTb, attnO);
  // output GEMM, 256x128 tile: grid 16 x 16 = 256 blocks
  gemm_bf16_f32<<<dim3(H_ / 128, M_ / 256, 1), 512, 0, stream>>>(
      attnO, woT, out, M_, H_, HQ_, AP_, AP_, H_, 0ull);
}

// Round 4
// 224.275 us; speedup vs baseline: 1.0745x; 1.0745x over previous
//
#include <hip/hip_runtime.h>

typedef float floatx4 __attribute__((ext_vector_type(4)));
typedef __bf16 bfx8 __attribute__((ext_vector_type(8)));
typedef __bf16 bfx4 __attribute__((ext_vector_type(4)));

// Problem constants
constexpr int B_ = 2, S_ = 2048, H_ = 2048, NH_ = 16, NKV_ = 4, HD_ = 64;
constexpr int M_ = B_ * S_;               // 4096 rows
constexpr int NQKV_ = NH_ * HD_ + 2 * NKV_ * HD_; // 1536
constexpr int HQ_ = NH_ * HD_;            // 1024
// Pitches: 128B-aligned (no cache-line straddle on 128B DMA row-chunks) AND an
// odd multiple of 64 elements (33x128B / 17x128B) to keep channel spread.
// (2056/1032 broke alignment: 4112B%128=16 -> every DMA chunk hit 2 lines.)
constexpr int XP_ = 2112;  // xbf / wqkvT pitch (4224B = 33*128)
constexpr int AP_ = 1088;  // attn-out / woT pitch (2176B = 17*128)
constexpr int VP_ = 2112;  // V-transposed pitch
// split-K partial stride (elements) for the QKV GEMM
constexpr int QKV_ELEMS_ = M_ * NQKV_;    // 6,291,456

#define GLB(p) ((const __attribute__((address_space(1))) void*)(p))
#define LDS(p) ((__attribute__((address_space(3))) void*)(p))

// ---------------- fused prep: fp32->bf16 cast of x  +  all 4 weight transposes ----------
__global__ __launch_bounds__(256) void prep_kernel(const float* __restrict__ x,
                                                   const float* __restrict__ wq,
                                                   const float* __restrict__ wk,
                                                   const float* __restrict__ wv,
                                                   const float* __restrict__ wo,
                                                   __bf16* __restrict__ xbf,
                                                   __bf16* __restrict__ wqkvT,
                                                   __bf16* __restrict__ woT) {
  __shared__ float tile[32][33];
  int bid = blockIdx.x;
  if (bid < M_) {
    // ---- cast branch ----
    const float4* s = (const float4*)(x + (size_t)bid * H_);
    __bf16* d = xbf + (size_t)bid * XP_;
#pragma unroll
    for (int i = 0; i < 2; i++) {
      int c = i * 256 + threadIdx.x;
      float4 v = s[c];
      bfx4 o;
      o[0] = (__bf16)v.x; o[1] = (__bf16)v.y; o[2] = (__bf16)v.z; o[3] = (__bf16)v.w;
      *(bfx4*)(d + c * 4) = o;
    }
    return;
  }
  bid -= M_;
  const float* src; __bf16* dst; int N, dstOff, pitch, nbx;
  if (bid < 2048)      { src = wq; dst = wqkvT; N = 1024; dstOff = 0;    pitch = XP_; nbx = 32; }
  else if (bid < 2560) { bid -= 2048; src = wk; dst = wqkvT; N = 256; dstOff = 1024; pitch = XP_; nbx = 8; }
  else if (bid < 3072) { bid -= 2560; src = wv; dst = wqkvT; N = 256; dstOff = 1280; pitch = XP_; nbx = 8; }
  else                 { bid -= 3072; src = wo; dst = woT;   N = 2048; dstOff = 0;   pitch = AP_; nbx = 64; }
  int n0 = (bid % nbx) * 32, k0 = (bid / nbx) * 32;
  int tx = threadIdx.x & 31, ty = threadIdx.x >> 5; // (32,8) layout
#pragma unroll
  for (int r = 0; r < 32; r += 8)
    tile[ty + r][tx] = src[(size_t)(k0 + ty + r) * N + n0 + tx];
  __syncthreads();
#pragma unroll
  for (int r = 0; r < 32; r += 8)
    dst[(size_t)(n0 + ty + r + dstOff) * pitch + k0 + tx] = (__bf16)tile[tx][ty + r];
}

// ---------------- bf16 MFMA GEMM: 256x128 tile, BK=64, 8 waves (4m x 2n) ------------
// A: MxK (lda), Bt: NxK (ldb), C: MxN fp32 (ldc). LDS unpadded (DMA dest =
// wave-uniform base + lane*16); XOR swizzle applied to the SOURCE address, undone on
// the fragment read. Split-K via blockIdx.z: [z*K,(z+1)*K) -> C + z*cstride.
__global__ __launch_bounds__(512) void gemm_bf16_f32(const __bf16* __restrict__ A,
                                                     const __bf16* __restrict__ Bt,
                                                     float* __restrict__ C,
                                                     int M, int N, int K,
                                                     int lda, int ldb, int ldc,
                                                     unsigned long long cstride) {
  __shared__ __align__(16) __bf16 As[256 * 64];
  __shared__ __align__(16) __bf16 Bs[128 * 64];
  int wid = threadIdx.x >> 6, lane = threadIdx.x & 63;
  int l15 = lane & 15, quad = lane >> 4;
  int wm = (wid >> 1) * 64, wn = (wid & 1) * 64; // 4m x 2n wave grid
  int m0 = blockIdx.y * 256, n0 = blockIdx.x * 128;
  int kb0 = blockIdx.z * K;
  C += (size_t)blockIdx.z * cstride;
  int srow_off = lane >> 3;  // 8 lanes per 64-col row (16B each)
  int gphys = lane & 7;
  floatx4 acc[4][4] = {};
  for (int kb = kb0; kb < kb0 + K; kb += 64) {
#pragma unroll
    for (int j = 0; j < 4; j++) {
      int rbase = j * 64 + wid * 8;
      int row = rbase + srow_off;
      int glog = gphys ^ (row & 7);
      const __bf16* ga = &A[(size_t)(m0 + row) * lda + kb + glog * 8];
      __builtin_amdgcn_global_load_lds(GLB(ga), LDS(&As[rbase * 64]), 16, 0, 0);
    }
#pragma unroll
    for (int j = 0; j < 2; j++) {
      int rbase = j * 64 + wid * 8;
      int row = rbase + srow_off;
      int glog = gphys ^ (row & 7);
      const __bf16* gb = &Bt[(size_t)(n0 + row) * ldb + kb + glog * 8];
      __builtin_amdgcn_global_load_lds(GLB(gb), LDS(&Bs[rbase * 64]), 16, 0, 0);
    }
    __syncthreads(); // compiler emits vmcnt(0) drain before barrier
#pragma unroll
    for (int kk = 0; kk < 64; kk += 32) {
      int cgq = (kk >> 3) + quad; // logical 16B-group of this quad's fragment
      bfx8 af[4], bfr[4];
#pragma unroll
      for (int mi = 0; mi < 4; mi++) {
        int row = wm + mi * 16 + l15;
        af[mi] = *(const bfx8*)&As[row * 64 + (cgq ^ (row & 7)) * 8];
      }
#pragma unroll
      for (int ni = 0; ni < 4; ni++) {
        int row = wn + ni * 16 + l15;
        bfr[ni] = *(const bfx8*)&Bs[row * 64 + (cgq ^ (row & 7)) * 8];
      }
#pragma unroll
      for (int mi = 0; mi < 4; mi++)
#pragma unroll
        for (int ni = 0; ni < 4; ni++)
          acc[mi][ni] = __builtin_amdgcn_mfma_f32_16x16x32_bf16(af[mi], bfr[ni], acc[mi][ni], 0, 0, 0);
    }
    __syncthreads();
  }
#pragma unroll
  for (int mi = 0; mi < 4; mi++)
#pragma unroll
    for (int ni = 0; ni < 4; ni++) {
      int row = m0 + wm + mi * 16 + quad * 4;
      int coln = n0 + wn + ni * 16 + l15;
#pragma unroll
      for (int r = 0; r < 4; r++)
        C[(size_t)(row + r) * ldc + coln] = acc[mi][ni][r];
    }
}

// ---------------- RMSNorm + RoPE on q/k, cast+layout for attention ----------------
// Reads TWO split-K partials of qkv and sums them (the split-K reduction is fused here).
__global__ __launch_bounds__(256) void norm_rope_kernel(const float* __restrict__ qkv,
                                                        const float* __restrict__ cosT,
                                                        const float* __restrict__ sinT,
                                                        const float* __restrict__ qw,
                                                        const float* __restrict__ kw,
                                                        __bf16* __restrict__ Qo,
                                                        __bf16* __restrict__ Ko,
                                                        __bf16* __restrict__ VTo) {
  int s = blockIdx.x, b = blockIdx.y;
  int wid = threadIdx.x >> 6, lane = threadIdx.x & 63;
  const float* rowp = qkv + (size_t)(b * S_ + s) * NQKV_;
  const float* rowp2 = rowp + QKV_ELEMS_;
  float c = cosT[s * HD_ + lane];
  float sn = sinT[s * HD_ + lane];
#pragma unroll
  for (int it = 0; it < 5; it++) {
    int hh = it * 4 + wid; // 0..15 q heads, 16..19 k heads
    int idx = hh * 64 + lane;
    float v = rowp[idx] + rowp2[idx];
    float ss = v * v;
#pragma unroll
    for (int off = 1; off < 64; off <<= 1) ss += __shfl_xor(ss, off);
    float rs = rsqrtf(ss * (1.0f / 64.0f) + 1e-6f);
    const float* w = (hh < 16) ? qw : kw;
    float nv = v * rs * w[lane];
    float other = __shfl_xor(nv, 32);
    float rot = (lane < 32) ? -other : other; // rotate_half
    float outv = nv * c + rot * sn;
    if (hh < 16)
      Qo[(((size_t)b * NH_ + hh) * S_ + s) * HD_ + lane] = (__bf16)outv;
    else
      Ko[(((size_t)b * NKV_ + (hh - 16)) * S_ + s) * HD_ + lane] = (__bf16)outv;
  }
  {
    int idx = (20 + wid) * 64 + lane;
    float v = rowp[idx] + rowp2[idx];
    VTo[(((size_t)b * NKV_ + wid) * HD_ + lane) * VP_ + s] = (__bf16)v;
  }
}

// ---------------- flash attention (causal, GQA), block-cooperative LDS staging ----------
// (round-2 structure: 4 waves, QBLK=64, reg-staged double-buffer — measured 45.8us)
__global__ __launch_bounds__(256, 4) void attn_kernel(const __bf16* __restrict__ Q,
                                                      const __bf16* __restrict__ Kc,
                                                      const __bf16* __restrict__ VT,
                                                      __bf16* __restrict__ Ob) {
  int px = blockIdx.x, h = blockIdx.y, b = blockIdx.z;
  int u = (px + 2 * (h & 7)) & 31;
  int qt = (((h >> 3) ^ b) & 1) ? (31 - u) : u;
  int wid = threadIdx.x >> 6, lane = threadIdx.x & 63;
  int l15 = lane & 15, quad = lane >> 4;
  int q0 = qt * 64 + wid * 16;
  int kvh = h >> 2; // N_REP = 4
  const __bf16* Qh = Q + (((size_t)b * NH_ + h) * S_ + q0) * HD_;
  const __bf16* Kh = Kc + ((size_t)b * NKV_ + kvh) * S_ * HD_;
  const __bf16* Vh = VT + ((size_t)b * NKV_ + kvh) * (size_t)HD_ * VP_;
  __shared__ __align__(16) __bf16 Ks[64][72]; // [kv][hd]
  __shared__ __align__(16) __bf16 Vs[64][72]; // [hd][kv]
  __shared__ __align__(16) __bf16 Pst[4][16][72];
  __bf16 (*P)[72] = Pst[wid];

  int srow = threadIdx.x >> 3;         // 0..31
  int scol = (threadIdx.x & 7) * 8;    // element offset 0..56

  bfx8 qf0, qf1;
  {
    const __bf16* qp = Qh + l15 * HD_ + quad * 8;
    qf0 = *(const bfx8*)qp;
    qf1 = *(const bfx8*)(qp + 32);
  }
  floatx4 oacc[4] = {};
  float ps = 0.f;
  int ntiles = qt + 1; // causal, block-uniform
  bfx8 kpre0, kpre1, vpre0, vpre1;
  kpre0 = *(const bfx8*)&Kh[(size_t)srow * HD_ + scol];
  kpre1 = *(const bfx8*)&Kh[(size_t)(srow + 32) * HD_ + scol];
  vpre0 = *(const bfx8*)&Vh[(size_t)srow * VP_ + scol];
  vpre1 = *(const bfx8*)&Vh[(size_t)(srow + 32) * VP_ + scol];
  for (int kt = 0; kt < ntiles; kt++) {
    int kv0 = kt * 64;
    int dq = q0 - kv0;
    __syncthreads();
    *(bfx8*)&Ks[srow][scol] = kpre0;
    *(bfx8*)&Ks[srow + 32][scol] = kpre1;
    *(bfx8*)&Vs[srow][scol] = vpre0;
    *(bfx8*)&Vs[srow + 32][scol] = vpre1;
    __syncthreads();
    if (kt + 1 < ntiles) {
      int kn = kv0 + 64;
      kpre0 = *(const bfx8*)&Kh[(size_t)(kn + srow) * HD_ + scol];
      kpre1 = *(const bfx8*)&Kh[(size_t)(kn + srow + 32) * HD_ + scol];
      vpre0 = *(const bfx8*)&Vh[(size_t)srow * VP_ + kn + scol];
      vpre1 = *(const bfx8*)&Vh[(size_t)(srow + 32) * VP_ + kn + scol];
    }
    floatx4 sf[4];
#pragma unroll
    for (int nt = 0; nt < 4; nt++) {
      bfx8 kf0 = *(const bfx8*)&Ks[nt * 16 + l15][quad * 8];
      bfx8 kf1 = *(const bfx8*)&Ks[nt * 16 + l15][32 + quad * 8];
      floatx4 z = {0.f, 0.f, 0.f, 0.f};
      z = __builtin_amdgcn_mfma_f32_16x16x32_bf16(kf0, qf0, z, 0, 0, 0);
      sf[nt] = __builtin_amdgcn_mfma_f32_16x16x32_bf16(kf1, qf1, z, 0, 0, 0);
    }
#pragma unroll
    for (int nt = 0; nt < 4; nt++) {
      bfx4 pk;
#pragma unroll
      for (int r = 0; r < 4; r++) {
        int kvrel = nt * 16 + quad * 4 + r;
        float p = __expf(sf[nt][r] * 0.125f);
        p = (kvrel - l15 > dq) ? 0.f : p;
        ps += p;
        pk[r] = (__bf16)p;
      }
      *(bfx4*)&P[l15][nt * 16 + quad * 4] = pk;
    }
    bfx8 pa0 = *(const bfx8*)&P[l15][quad * 8];
    bfx8 pa1 = *(const bfx8*)&P[l15][32 + quad * 8];
#pragma unroll
    for (int ot = 0; ot < 4; ot++) {
      bfx8 vf0 = *(const bfx8*)&Vs[ot * 16 + l15][quad * 8];
      bfx8 vf1 = *(const bfx8*)&Vs[ot * 16 + l15][32 + quad * 8];
      oacc[ot] = __builtin_amdgcn_mfma_f32_16x16x32_bf16(pa0, vf0, oacc[ot], 0, 0, 0);
      oacc[ot] = __builtin_amdgcn_mfma_f32_16x16x32_bf16(pa1, vf1, oacc[ot], 0, 0, 0);
    }
  }
  ps += __shfl_xor(ps, 16);
  ps += __shfl_xor(ps, 32);
  float rl[4];
#pragma unroll
  for (int r = 0; r < 4; r++) rl[r] = 1.0f / __shfl(ps, quad * 4 + r);
#pragma unroll
  for (int ot = 0; ot < 4; ot++)
#pragma unroll
    for (int r = 0; r < 4; r++) {
      float val = oacc[ot][r] * rl[r];
      Ob[((size_t)b * S_ + q0 + quad * 4 + r) * AP_ + h * HD_ + ot * 16 + l15] = (__bf16)val;
    }
}

extern "C" void kernel_launch(void* const* d_in, const int* in_sizes, int n_in,
                              void* d_out, int out_size, void* d_ws, size_t ws_size,
                              hipStream_t stream) {
  const float* x   = (const float*)d_in[0];
  const float* cosT = (const float*)d_in[1];
  const float* sinT = (const float*)d_in[2];
  const float* wq  = (const float*)d_in[3];
  const float* wk  = (const float*)d_in[4];
  const float* wv  = (const float*)d_in[5];
  const float* wo  = (const float*)d_in[6];
  const float* qw  = (const float*)d_in[7];
  const float* kw  = (const float*)d_in[8];
  float* out = (float*)d_out;

  char* w = (char*)d_ws;
  // Lifetime-packed workspace:
  //   xbf [0, 17,301,504)  dead after gemm1; Qb/Kb/VTb reuse it (written by norm_rope)
  __bf16* xbf   = (__bf16*)(w);                        // 4096*2112*2 = 17,301,504
  __bf16* Qb    = (__bf16*)(w);                        //  8,388,608 (aliases dead xbf)
  __bf16* Kb    = (__bf16*)(w + 8388608);              //  2,097,152
  __bf16* VTb   = (__bf16*)(w + 10485760);             //  2*4*64*2112*2 = 2,162,688 (end 12,648,448)
  __bf16* wqkvT = (__bf16*)(w + 17301504);             // 1536*2112*2 = 6,488,064
  __bf16* woT   = (__bf16*)(w + 23789568);             // 2048*1088*2 = 4,456,448
  float*  qkv   = (float*) (w + 28246016);             // 2 splits * 4096*1536*4 = 50,331,648
  __bf16* attnO = (__bf16*)(w + 28246016);             // aliases qkv (dead after norm_rope)
                                                       // total end = 78,577,664

  // fused prep: cast (4096 blocks) + wq/wk/wv/wo transposes (2048+512+512+2048)
  prep_kernel<<<M_ + 5120, 256, 0, stream>>>(x, wq, wk, wv, wo, xbf, wqkvT, woT);
  // QKV GEMM, 256x128 tile, split-K=2: grid 12 x 16 x 2 = 384 blocks
  gemm_bf16_f32<<<dim3(NQKV_ / 128, M_ / 256, 2), 512, 0, stream>>>(
      xbf, wqkvT, qkv, M_, NQKV_, H_ / 2, XP_, XP_, NQKV_, (unsigned long long)QKV_ELEMS_);
  norm_rope_kernel<<<dim3(S_, B_), 256, 0, stream>>>(qkv, cosT, sinT, qw, kw, Qb, Kb, VTb);
  // attention: QBLK=64, 4 waves, grid 32 x 16 x 2 = 1024 blocks
  attn_kernel<<<dim3(32, NH_, B_), 256, 0, stream>>>(Qb, Kb, VTb, attnO);
  // output GEMM, 256x128 tile: grid 16 x 16 = 256 blocks
  gemm_bf16_f32<<<dim3(H_ / 128, M_ / 256, 1), 512, 0, stream>>>(
      attnO, woT, out, M_, H_, HQ_, AP_, AP_, H_, 0ull);
}